// Round 5
// baseline (1103.341 us; speedup 1.0000x reference)
//
#include <hip/hip_runtime.h>
#include <hip/hip_bf16.h>

typedef __attribute__((ext_vector_type(8))) short short8;
typedef __attribute__((ext_vector_type(4))) float f32x4;

static __device__ __forceinline__ short f2bf(float f) {
    union { __hip_bfloat16 h; short s; } u;
    u.h = __float2bfloat16(f);
    return u.s;
}

static __device__ __forceinline__ float gelu_tanh(float v) {
    const float c = 0.7978845608028654f;
    float t = tanhf(c * (v + 0.044715f * v * v * v));
    return 0.5f * v * (1.f + t);
}

// direct global->LDS DMA, 16B per lane per issue
static __device__ __forceinline__ void gload16(const void* g, void* l) {
    __builtin_amdgcn_global_load_lds(
        (const __attribute__((address_space(1))) void*)g,
        (__attribute__((address_space(3))) void*)l, 16, 0, 0);
}

// ---------------- weight convert + transpose (runs every launch; ws is re-poisoned) ----------
__global__ __launch_bounds__(256) void cvt_weights(
    const float* __restrict__ wq, const float* __restrict__ wk,
    const float* __restrict__ wv, const float* __restrict__ wo,
    const float* __restrict__ w1, const float* __restrict__ w2,
    short* __restrict__ wT)
{
    const long NSQ = 12L * 262144;
    long gid = (long)blockIdx.x * 256 + threadIdx.x;
    if (gid < NSQ) {
        int m = (int)(gid >> 18);
        int rem = (int)(gid & 262143);
        int n = rem >> 9, k = rem & 511;          // dst [n][k]
        int a = m >> 2, t = m & 3;
        const float* src = (t == 0) ? wq : (t == 1) ? wk : (t == 2) ? wv : wo;
        wT[gid] = f2bf(src[(long)a * 262144 + (long)k * 512 + n]);
    } else if (gid < NSQ + 1048576) {
        int r = (int)(gid - NSQ);
        int n = r >> 9, k = r & 511;              // w1T [2048][512]
        wT[gid] = f2bf(w1[(long)k * 2048 + n]);
    } else {
        int r = (int)(gid - NSQ - 1048576);
        int n = r >> 11, k = r & 2047;            // w2T [512][2048]
        wT[gid] = f2bf(w2[(long)k * 512 + n]);
    }
}

// ---------------- LayerNorm (fp32 in, bf16 out), one wave per row of 512 ----------
__global__ __launch_bounds__(256) void ln_kernel(
    const float* __restrict__ x, const float* __restrict__ sc,
    const float* __restrict__ bi, short* __restrict__ out)
{
    int row = blockIdx.x * 4 + (threadIdx.x >> 6);
    int lane = threadIdx.x & 63;
    const float* xr = x + (long)row * 512 + lane * 8;
    f32x4 v0 = *(const f32x4*)xr;
    f32x4 v1 = *(const f32x4*)(xr + 4);
    float s = 0.f, ss = 0.f;
#pragma unroll
    for (int i = 0; i < 4; i++) { s += v0[i] + v1[i]; ss += v0[i] * v0[i] + v1[i] * v1[i]; }
#pragma unroll
    for (int m = 1; m < 64; m <<= 1) { s += __shfl_xor(s, m, 64); ss += __shfl_xor(ss, m, 64); }
    float mean = s * (1.f / 512.f);
    float var  = ss * (1.f / 512.f) - mean * mean;
    float rs = rsqrtf(var + 1e-6f);
    f32x4 s0 = *(const f32x4*)(sc + lane * 8);
    f32x4 s1 = *(const f32x4*)(sc + lane * 8 + 4);
    f32x4 b0 = *(const f32x4*)(bi + lane * 8);
    f32x4 b1 = *(const f32x4*)(bi + lane * 8 + 4);
    short8 o;
#pragma unroll
    for (int i = 0; i < 4; i++) o[i]     = f2bf((v0[i] - mean) * rs * s0[i] + b0[i]);
#pragma unroll
    for (int i = 0; i < 4; i++) o[4 + i] = f2bf((v1[i] - mean) * rs * s1[i] + b1[i]);
    *(short8*)(out + (long)row * 512 + lane * 8) = o;
}

// ---------------- GEMM: C[M][N] = A[M][K] * Bt[N][K]^T, bf16 in, fp32 acc ----------
// m97 structure: 128x128 tile, BK=64, 4 waves, global_load_lds width=16, linear LDS.
// No XCD swizzle (measured: hurt L3 locality on these skinny GEMMs, R4).
// EPI 1: outf[idx] = acc + bias[col] + res[idx]   (fp32 out, scalar stores = full 64B lines)
// EPI 2: outb = bf16(gelu(acc+bias))              (bf16 out, LDS-transposed vector stores)
// EPI 3: QKV combined: part=col>>9 -> bias1/2/3; part 0 scaled; bf16 out (vector stores)
template<int EPI>
__global__ __launch_bounds__(256, 2) void gemm_nt(
    const short* __restrict__ A, const short* __restrict__ Bt,
    const float* __restrict__ bias, const float* __restrict__ bias2,
    const float* __restrict__ bias3,
    const float* __restrict__ res, float* __restrict__ outf,
    short* __restrict__ outb, int M, int N, int K, float scale)
{
    __shared__ __align__(16) short As[128 * 64];
    __shared__ __align__(16) short Bs[128 * 64];
    const int t = threadIdx.x;
    const int lane = t & 63, wid = t >> 6;
    const int wm = wid >> 1, wn = wid & 1;
    const int m0 = blockIdx.x * 128, n0 = blockIdx.y * 128;

    const short* Ag = A  + (long)m0 * K;
    const short* Bg = Bt + (long)n0 * K;

    f32x4 acc[4][4];
#pragma unroll
    for (int i = 0; i < 4; i++)
#pragma unroll
        for (int j = 0; j < 4; j++) acc[i][j] = (f32x4){0.f, 0.f, 0.f, 0.f};

    // staging geometry: issue c (0..3), thread t -> row c*32 + (t>>3), 16B chunk t&7
    const long rowOff = (long)(t >> 3) * K + (t & 7) * 8;
    const int  ldsOff = t * 16;
    const int NT = K >> 6;

    for (int tt = 0; tt < NT; ++tt) {
        const short* Asrc = Ag + tt * 64 + rowOff;
        const short* Bsrc = Bg + tt * 64 + rowOff;
#pragma unroll
        for (int c = 0; c < 4; c++) {
            gload16(Asrc + (long)c * 32 * K, (char*)As + c * 4096 + ldsOff);
            gload16(Bsrc + (long)c * 32 * K, (char*)Bs + c * 4096 + ldsOff);
        }
        __syncthreads();   // compiler emits s_waitcnt vmcnt(0) before barrier

        const int arow = wm * 64 + (lane & 15);
        const int brow = wn * 64 + (lane & 15);
        const int kb = (lane >> 4) * 16;   // byte offset of this lane's k-chunk
#pragma unroll
        for (int ks = 0; ks < 2; ++ks) {
            short8 af[4], bfr[4];
#pragma unroll
            for (int f = 0; f < 4; f++) {
                af[f]  = *(short8*)((char*)As + (arow + f * 16) * 128 + kb + ks * 64);
                bfr[f] = *(short8*)((char*)Bs + (brow + f * 16) * 128 + kb + ks * 64);
            }
#pragma unroll
            for (int i = 0; i < 4; i++)
#pragma unroll
                for (int j = 0; j < 4; j++)
                    acc[i][j] = __builtin_amdgcn_mfma_f32_16x16x32_bf16(af[i], bfr[j], acc[i][j], 0, 0, 0);
        }
        __syncthreads();
    }

    // ---------------- epilogue; C/D layout: col=lane&15, row=(lane>>4)*4+r ----------
    if (EPI == 1) {
        // fp32 out + residual: scalar path; each 16-lane quad writes a full 64B line
#pragma unroll
        for (int j = 0; j < 4; j++) {
            int col = n0 + wn * 64 + j * 16 + (lane & 15);
            float bv = bias[col];
#pragma unroll
            for (int i = 0; i < 4; i++) {
                int row0 = m0 + wm * 64 + i * 16 + ((lane >> 4) << 2);
#pragma unroll
                for (int r = 0; r < 4; r++) {
                    long idx = (long)(row0 + r) * N + col;
                    outf[idx] = acc[i][j][r] + bv + res[idx];
                }
            }
        }
    } else {
        // bf16 out: transpose each wave's 64x64 tile through its own 8KB LDS slice,
        // then 4-lane clusters store full 64B lines (short8 x4).
        float* sl = (float*)(wid < 2 ? (void*)As : (void*)Bs) + (wid & 1) * 2048;
        const int r0g = m0 + wm * 64;
        const int c0g = n0 + wn * 64;
#pragma unroll
        for (int half = 0; half < 2; ++half) {
#pragma unroll
            for (int jj = 0; jj < 2; ++jj) {
                int j = half * 2 + jj;
                int col = c0g + j * 16 + (lane & 15);
                float bv, sc_part = 1.f;
                if (EPI == 3) {
                    int part = col >> 9;
                    const float* bp = (part == 0) ? bias : (part == 1) ? bias2 : bias3;
                    bv = bp[col & 511];
                    if (part == 0) sc_part = scale;
                } else {
                    bv = bias[col];
                }
#pragma unroll
                for (int i = 0; i < 4; i++)
#pragma unroll
                    for (int r = 0; r < 4; r++) {
                        int rl = i * 16 + ((lane >> 4) << 2) + r;   // 0..63
                        int cl = jj * 16 + (lane & 15);             // 0..31
                        float v = (acc[i][j][r] + bv) * sc_part;
                        if (EPI == 2) v = gelu_tanh(v);
                        sl[(rl * 32 + cl) ^ ((rl & 7) << 2)] = v;
                    }
            }
            __syncthreads();   // order LDS write->read across halves (uniform)
#pragma unroll
            for (int s = 0; s < 4; s++) {
                int rl = s * 16 + (lane >> 2);
                int fb = rl * 32 + (lane & 3) * 8;
                int sw = (rl & 7) << 2;
                f32x4 lo = *(f32x4*)&sl[fb ^ sw];
                f32x4 hi = *(f32x4*)&sl[(fb + 4) ^ sw];
                short8 o;
#pragma unroll
                for (int e = 0; e < 4; e++) { o[e] = f2bf(lo[e]); o[4 + e] = f2bf(hi[e]); }
                *(short8*)(outb + (long)(r0g + rl) * N + c0g + half * 32 + (lane & 3) * 8) = o;
            }
            if (half == 0) __syncthreads();   // WAR: half-1 writes vs half-0 reads
        }
    }
}

// ---------------- axial attention: one wave per (sequence, head) ----------
// PASS 0: time  (S=16, stride 1024); PASS 1: height (S=32, stride 32); PASS 2: width (S=32, stride 1)
template<int S, int PASS>
__global__ __launch_bounds__(64) void attn_kernel(
    const short* __restrict__ Q, const short* __restrict__ Kx,
    const short* __restrict__ V, short* __restrict__ O, int ld)
{
    constexpr int MF = S / 16;
    constexpr int SP = 32;
    __shared__ __align__(16) short P_lds[S * SP];
    __shared__ __align__(16) short Vt[64 * SP];

    const int lane = threadIdx.x;
    const int pair = blockIdx.x;
    const int head = pair & 7;
    const int bf = pair >> 3;
    long base; int stride;
    if (PASS == 0)      { base = (long)(bf >> 10) * 16384 + (bf & 1023); stride = 1024; }
    else if (PASS == 1) { int b = bf >> 9, t = (bf >> 5) & 15, w = bf & 31; base = (long)b * 16384 + t * 1024 + w; stride = 32; }
    else                { int b = bf >> 9, t = (bf >> 5) & 15, h = bf & 31; base = (long)b * 16384 + t * 1024 + (h << 5); stride = 1; }
    const int hoff = head * 64;

    if (S == 16) {   // zero-pad P (k>=16) and Vt (kv>=16)
        short8 z = {0, 0, 0, 0, 0, 0, 0, 0};
        *(short8*)(P_lds + lane * 8) = z;
#pragma unroll
        for (int i = 0; i < 4; i++) *(short8*)(Vt + lane * 32 + i * 8) = z;
        __syncthreads();
    }

    // Q/K fragments: A lane holds A[lane&15][(lane>>4)*8+e]; B lane holds B[(lane>>4)*8+e][lane&15]=K[lane&15][k]
    short8 qf[MF][2], kf[MF][2];
#pragma unroll
    for (int f = 0; f < MF; f++) {
        int r = f * 16 + (lane & 15);
        const short* qp = Q + (base + (long)r * stride) * ld + hoff + ((lane >> 4) * 8);
        qf[f][0] = *(const short8*)qp;
        qf[f][1] = *(const short8*)(qp + 32);
        const short* kp = Kx + (base + (long)r * stride) * ld + hoff + ((lane >> 4) * 8);
        kf[f][0] = *(const short8*)kp;
        kf[f][1] = *(const short8*)(kp + 32);
    }

    // stage V^T into LDS
    short8 vv[4];
    const int vr  = (S == 32) ? (lane & 31) : (lane & 15);
    const int vd0 = (S == 32) ? ((lane >> 5) * 32) : ((lane >> 4) * 16);
    constexpr int NVC = (S == 32) ? 4 : 2;
    {
        const short* vp = V + (base + (long)vr * stride) * ld + hoff + vd0;
#pragma unroll
        for (int c = 0; c < NVC; c++) vv[c] = *(const short8*)(vp + c * 8);
    }
#pragma unroll
    for (int c = 0; c < NVC; c++)
#pragma unroll
        for (int e = 0; e < 8; e++)
            Vt[(vd0 + c * 8 + e) * SP + vr] = vv[c][e];

    // scores S[q][k] = sum_d Q[q][d] K[k][d]
    f32x4 zero4 = {0.f, 0.f, 0.f, 0.f};
    f32x4 sc[MF][MF];
#pragma unroll
    for (int i = 0; i < MF; i++)
#pragma unroll
        for (int j = 0; j < MF; j++) {
            f32x4 a = __builtin_amdgcn_mfma_f32_16x16x32_bf16(qf[i][0], kf[j][0], zero4, 0, 0, 0);
            sc[i][j] = __builtin_amdgcn_mfma_f32_16x16x32_bf16(qf[i][1], kf[j][1], a, 0, 0, 0);
        }

    // softmax over k (cols); row = i*16 + (lane>>4)*4 + r, col = (lane&15) + 16*j
#pragma unroll
    for (int i = 0; i < MF; i++) {
#pragma unroll
        for (int r = 0; r < 4; r++) {
            float mx = sc[i][0][r];
            if (MF == 2) mx = fmaxf(mx, sc[i][1][r]);
#pragma unroll
            for (int m = 1; m < 16; m <<= 1) mx = fmaxf(mx, __shfl_xor(mx, m, 64));
            float e0 = expf(sc[i][0][r] - mx);
            float e1 = (MF == 2) ? expf(sc[i][1][r] - mx) : 0.f;
            float sum = e0 + e1;
#pragma unroll
            for (int m = 1; m < 16; m <<= 1) sum += __shfl_xor(sum, m, 64);
            float inv = 1.f / sum;
            int row = i * 16 + ((lane >> 4) << 2) + r;
            P_lds[row * SP + (lane & 15)] = f2bf(e0 * inv);
            if (MF == 2) P_lds[row * SP + 16 + (lane & 15)] = f2bf(e1 * inv);
        }
    }
    __syncthreads();

    // O = P (M=S,K=SP) * V (SP x 64)
    short8 pa[MF];
#pragma unroll
    for (int f = 0; f < MF; f++)
        pa[f] = *(const short8*)(P_lds + (f * 16 + (lane & 15)) * SP + (lane >> 4) * 8);
    short8 vbf[4];
#pragma unroll
    for (int n = 0; n < 4; n++)
        vbf[n] = *(const short8*)(Vt + (n * 16 + (lane & 15)) * SP + (lane >> 4) * 8);
    f32x4 of[MF][4];
#pragma unroll
    for (int f = 0; f < MF; f++)
#pragma unroll
        for (int n = 0; n < 4; n++)
            of[f][n] = __builtin_amdgcn_mfma_f32_16x16x32_bf16(pa[f], vbf[n], zero4, 0, 0, 0);

#pragma unroll
    for (int f = 0; f < MF; f++) {
        int q0 = f * 16 + ((lane >> 4) << 2);
#pragma unroll
        for (int n = 0; n < 4; n++) {
            int d = n * 16 + (lane & 15);
#pragma unroll
            for (int r = 0; r < 4; r++)
                O[(base + (long)(q0 + r) * stride) * 512 + hoff + d] = f2bf(of[f][n][r]);
        }
    }
}

// ---------------- launch ----------
extern "C" void kernel_launch(void* const* d_in, const int* in_sizes, int n_in,
                              void* d_out, int out_size, void* d_ws, size_t ws_size,
                              hipStream_t stream)
{
    const float* x   = (const float*)d_in[0];
    const float* lns = (const float*)d_in[1];
    const float* lnb = (const float*)d_in[2];
    const float* wq  = (const float*)d_in[3];
    const float* bq  = (const float*)d_in[4];
    const float* wk  = (const float*)d_in[5];
    const float* bk  = (const float*)d_in[6];
    const float* wv  = (const float*)d_in[7];
    const float* bv  = (const float*)d_in[8];
    const float* wo  = (const float*)d_in[9];
    const float* bo  = (const float*)d_in[10];
    const float* lms = (const float*)d_in[11];
    const float* lmb = (const float*)d_in[12];
    const float* w1  = (const float*)d_in[13];
    const float* b1  = (const float*)d_in[14];
    const float* w2  = (const float*)d_in[15];
    const float* b2  = (const float*)d_in[16];

    char* ws = (char*)d_ws;
    short* wT   = (short*)ws;                          // 10,485,760 B
    short* bufA = (short*)(ws + 10485760);             // 33,554,432 B  (LN out / attn out)
    short* big  = (short*)(ws + 10485760 + 33554432);  // 134,217,728 B (QKV [M][1536] then h1 [M][2048])
    float* xcur = (float*)d_out;                       // fp32 residual stream lives in d_out

    const int M = 32768;

    cvt_weights<<<20480, 256, 0, stream>>>(wq, wk, wv, wo, w1, w2, wT);

    for (int p = 0; p < 3; ++p) {
        const float* xin = (p == 0) ? x : xcur;
        ln_kernel<<<8192, 256, 0, stream>>>(xin, lns + p * 512, lnb + p * 512, bufA);
        const short* wqkvT = wT + (long)(p * 4) * 262144;      // q,k,v contiguous [1536][512]
        const short* woT   = wT + (long)(p * 4 + 3) * 262144;
        gemm_nt<3><<<dim3(256, 12), 256, 0, stream>>>(bufA, wqkvT,
            bq + p * 512, bk + p * 512, bv + p * 512,
            nullptr, nullptr, big, M, 1536, 512, 0.125f);
        const short* qb = big, *kb = big + 512, *vbp = big + 1024;
        if (p == 0)      attn_kernel<16, 0><<<16384, 64, 0, stream>>>(qb, kb, vbp, bufA, 1536);
        else if (p == 1) attn_kernel<32, 1><<<8192, 64, 0, stream>>>(qb, kb, vbp, bufA, 1536);
        else             attn_kernel<32, 2><<<8192, 64, 0, stream>>>(qb, kb, vbp, bufA, 1536);
        gemm_nt<1><<<dim3(256, 4), 256, 0, stream>>>(bufA, woT,
            bo + p * 512, nullptr, nullptr, xin, xcur, nullptr, M, 512, 512, 1.f);
    }

    ln_kernel<<<8192, 256, 0, stream>>>(xcur, lms, lmb, bufA);
    const short* w1T = wT + 12L * 262144;
    const short* w2T = wT + 12L * 262144 + 1048576;
    gemm_nt<2><<<dim3(256, 16), 256, 0, stream>>>(bufA, w1T, b1,
        nullptr, nullptr, nullptr, nullptr, big, M, 2048, 512, 1.f);
    gemm_nt<1><<<dim3(256, 4), 256, 0, stream>>>(big, w2T, b2,
        nullptr, nullptr, xcur, xcur, nullptr, M, 512, 2048, 1.f);
}

// Round 7
// 904.557 us; speedup vs baseline: 1.2198x; 1.2198x over previous
//
#include <hip/hip_runtime.h>
#include <hip/hip_bf16.h>

typedef __attribute__((ext_vector_type(8))) short short8;
typedef __attribute__((ext_vector_type(4))) float f32x4;

static __device__ __forceinline__ short f2bf(float f) {
    union { __hip_bfloat16 h; short s; } u;
    u.h = __float2bfloat16(f);
    return u.s;
}

static __device__ __forceinline__ float gelu_tanh(float v) {
    const float c = 0.7978845608028654f;
    float t = tanhf(c * (v + 0.044715f * v * v * v));
    return 0.5f * v * (1.f + t);
}

// ---------------- weight convert + transpose (runs every launch; ws is re-poisoned) ----------
__global__ __launch_bounds__(256) void cvt_weights(
    const float* __restrict__ wq, const float* __restrict__ wk,
    const float* __restrict__ wv, const float* __restrict__ wo,
    const float* __restrict__ w1, const float* __restrict__ w2,
    short* __restrict__ wT)
{
    const long NSQ = 12L * 262144;
    long gid = (long)blockIdx.x * 256 + threadIdx.x;
    if (gid < NSQ) {
        int m = (int)(gid >> 18);
        int rem = (int)(gid & 262143);
        int n = rem >> 9, k = rem & 511;          // dst [n][k]
        int a = m >> 2, t = m & 3;
        const float* src = (t == 0) ? wq : (t == 1) ? wk : (t == 2) ? wv : wo;
        wT[gid] = f2bf(src[(long)a * 262144 + (long)k * 512 + n]);
    } else if (gid < NSQ + 1048576) {
        int r = (int)(gid - NSQ);
        int n = r >> 9, k = r & 511;              // w1T [2048][512]
        wT[gid] = f2bf(w1[(long)k * 2048 + n]);
    } else {
        int r = (int)(gid - NSQ - 1048576);
        int n = r >> 11, k = r & 2047;            // w2T [512][2048]
        wT[gid] = f2bf(w2[(long)k * 512 + n]);
    }
}

// ---------------- LayerNorm (fp32 in, bf16 out), one wave per row of 512 ----------
__global__ __launch_bounds__(256) void ln_kernel(
    const float* __restrict__ x, const float* __restrict__ sc,
    const float* __restrict__ bi, short* __restrict__ out)
{
    int row = blockIdx.x * 4 + (threadIdx.x >> 6);
    int lane = threadIdx.x & 63;
    const float* xr = x + (long)row * 512 + lane * 8;
    f32x4 v0 = *(const f32x4*)xr;
    f32x4 v1 = *(const f32x4*)(xr + 4);
    float s = 0.f, ss = 0.f;
#pragma unroll
    for (int i = 0; i < 4; i++) { s += v0[i] + v1[i]; ss += v0[i] * v0[i] + v1[i] * v1[i]; }
#pragma unroll
    for (int m = 1; m < 64; m <<= 1) { s += __shfl_xor(s, m, 64); ss += __shfl_xor(ss, m, 64); }
    float mean = s * (1.f / 512.f);
    float var  = ss * (1.f / 512.f) - mean * mean;
    float rs = rsqrtf(var + 1e-6f);
    f32x4 s0 = *(const f32x4*)(sc + lane * 8);
    f32x4 s1 = *(const f32x4*)(sc + lane * 8 + 4);
    f32x4 b0 = *(const f32x4*)(bi + lane * 8);
    f32x4 b1 = *(const f32x4*)(bi + lane * 8 + 4);
    short8 o;
#pragma unroll
    for (int i = 0; i < 4; i++) o[i]     = f2bf((v0[i] - mean) * rs * s0[i] + b0[i]);
#pragma unroll
    for (int i = 0; i < 4; i++) o[4 + i] = f2bf((v1[i] - mean) * rs * s1[i] + b1[i]);
    *(short8*)(out + (long)row * 512 + lane * 8) = o;
}

// ---------------- GEMM: C[M][N] = A[M][K] * Bt[N][K]^T, bf16 in, fp32 acc ----------
// Reg-staged prefetch loop (R2 structure, measured-best total): global loads for
// tile t+1 issue BEFORE barrier1 of tile t, overlapping barrier+MFMA (T14-style).
// No XCD swizzle (R4: hurt L3). Vectorized LDS-transpose epilogue for bf16 outputs
// (R5: halves HBM write traffic, full 64B-line stores).
// EPI 1: outf[idx] = acc + bias[col] + res[idx]   (fp32 out)
// EPI 2: outb = bf16(gelu(acc+bias))              (bf16 out, vector stores)
// EPI 3: QKV: part=col>>9 -> bias1/2/3; part 0 scaled; bf16 out (vector stores)
template<int EPI>
__global__ __launch_bounds__(256, 2) void gemm_nt(
    const short* __restrict__ A, const short* __restrict__ Bt,
    const float* __restrict__ bias, const float* __restrict__ bias2,
    const float* __restrict__ bias3,
    const float* __restrict__ res, float* __restrict__ outf,
    short* __restrict__ outb, int M, int N, int K, float scale)
{
    __shared__ __align__(16) short As[128 * 64];
    __shared__ __align__(16) short Bs[128 * 64];
    const int t = threadIdx.x;
    const int lane = t & 63, wid = t >> 6;
    const int wm = wid >> 1, wn = wid & 1;
    const int m0 = blockIdx.x * 128, n0 = blockIdx.y * 128;

    const short* Ag = A  + (long)m0 * K;
    const short* Bg = Bt + (long)n0 * K;

    f32x4 acc[4][4];
#pragma unroll
    for (int i = 0; i < 4; i++)
#pragma unroll
        for (int j = 0; j < 4; j++) acc[i][j] = (f32x4){0.f, 0.f, 0.f, 0.f};

    short8 areg[4], breg[4];
#pragma unroll
    for (int c = 0; c < 4; c++) {
        int g = c * 256 + t; int r = g >> 3, kc = g & 7;
        areg[c] = *(const short8*)(Ag + (long)r * K + kc * 8);
        breg[c] = *(const short8*)(Bg + (long)r * K + kc * 8);
    }
    const int NT = K >> 6;
    for (int tt = 0; tt < NT; ++tt) {
        // write tile t from regs to LDS (T2 XOR swizzle, write+read matched)
#pragma unroll
        for (int c = 0; c < 4; c++) {
            int g = c * 256 + t; int r = g >> 3, kc = g & 7;
            int off = r * 128 + ((kc * 16) ^ ((r & 7) << 4));
            *(short8*)((char*)As + off) = areg[c];
            *(short8*)((char*)Bs + off) = breg[c];
        }
        // issue tile t+1 global loads BEFORE the barrier: overlap barrier + MFMA
        if (tt + 1 < NT) {
            const short* Ag2 = Ag + (tt + 1) * 64;
            const short* Bg2 = Bg + (tt + 1) * 64;
#pragma unroll
            for (int c = 0; c < 4; c++) {
                int g = c * 256 + t; int r = g >> 3, kc = g & 7;
                areg[c] = *(const short8*)(Ag2 + (long)r * K + kc * 8);
                breg[c] = *(const short8*)(Bg2 + (long)r * K + kc * 8);
            }
        }
        __syncthreads();
        const int arow = wm * 64 + (lane & 15);
        const int brow = wn * 64 + (lane & 15);
        const int kb = (lane >> 4) * 16;   // byte offset of this lane's k-chunk
#pragma unroll
        for (int ks = 0; ks < 2; ++ks) {
            short8 af[4], bfr[4];
#pragma unroll
            for (int f = 0; f < 4; f++) {
                int ra = arow + f * 16;
                af[f]  = *(short8*)((char*)As + ra * 128 + ((kb + ks * 64) ^ ((ra & 7) << 4)));
                int rb = brow + f * 16;
                bfr[f] = *(short8*)((char*)Bs + rb * 128 + ((kb + ks * 64) ^ ((rb & 7) << 4)));
            }
#pragma unroll
            for (int i = 0; i < 4; i++)
#pragma unroll
                for (int j = 0; j < 4; j++)
                    acc[i][j] = __builtin_amdgcn_mfma_f32_16x16x32_bf16(af[i], bfr[j], acc[i][j], 0, 0, 0);
        }
        __syncthreads();   // protects LDS writes of next iteration (WAR)
    }

    // ---------------- epilogue; C/D layout: col=lane&15, row=(lane>>4)*4+r ----------
    if (EPI == 1) {
        // fp32 out + residual: each 16-lane quad writes a full 64B line
#pragma unroll
        for (int j = 0; j < 4; j++) {
            int col = n0 + wn * 64 + j * 16 + (lane & 15);
            float bv = bias[col];
#pragma unroll
            for (int i = 0; i < 4; i++) {
                int row0 = m0 + wm * 64 + i * 16 + ((lane >> 4) << 2);
#pragma unroll
                for (int r = 0; r < 4; r++) {
                    long idx = (long)(row0 + r) * N + col;
                    outf[idx] = acc[i][j][r] + bv + res[idx];
                }
            }
        }
    } else {
        // bf16 out: transpose each wave's 64x64 tile through its own 8KB LDS slice,
        // then 4-lane clusters store full 64B lines (short8 x4).
        float* sl = (float*)(wid < 2 ? (void*)As : (void*)Bs) + (wid & 1) * 2048;
        const int r0g = m0 + wm * 64;
        const int c0g = n0 + wn * 64;
#pragma unroll
        for (int half = 0; half < 2; ++half) {
#pragma unroll
            for (int jj = 0; jj < 2; ++jj) {
                int j = half * 2 + jj;
                int col = c0g + j * 16 + (lane & 15);
                float bv, sc_part = 1.f;
                if (EPI == 3) {
                    int part = col >> 9;
                    const float* bp = (part == 0) ? bias : (part == 1) ? bias2 : bias3;
                    bv = bp[col & 511];
                    if (part == 0) sc_part = scale;
                } else {
                    bv = bias[col];
                }
#pragma unroll
                for (int i = 0; i < 4; i++)
#pragma unroll
                    for (int r = 0; r < 4; r++) {
                        int rl = i * 16 + ((lane >> 4) << 2) + r;   // 0..63
                        int cl = jj * 16 + (lane & 15);             // 0..31
                        float v = (acc[i][j][r] + bv) * sc_part;
                        if (EPI == 2) v = gelu_tanh(v);
                        sl[(rl * 32 + cl) ^ ((rl & 7) << 2)] = v;
                    }
            }
            __syncthreads();   // order LDS write->read (uniform across block)
#pragma unroll
            for (int s = 0; s < 4; s++) {
                int rl = s * 16 + (lane >> 2);
                int fb = rl * 32 + (lane & 3) * 8;
                int sw = (rl & 7) << 2;
                f32x4 lo = *(f32x4*)&sl[fb ^ sw];
                f32x4 hi = *(f32x4*)&sl[(fb + 4) ^ sw];
                short8 o;
#pragma unroll
                for (int e = 0; e < 4; e++) { o[e] = f2bf(lo[e]); o[4 + e] = f2bf(hi[e]); }
                *(short8*)(outb + (long)(r0g + rl) * N + c0g + half * 32 + (lane & 3) * 8) = o;
            }
            if (half == 0) __syncthreads();   // WAR: half-1 writes vs half-0 reads
        }
    }
}

// ---------------- axial attention: one wave per (sequence, head) ----------
// PASS 0: time  (S=16, stride 1024); PASS 1: height (S=32, stride 32); PASS 2: width (S=32, stride 1)
template<int S, int PASS>
__global__ __launch_bounds__(64) void attn_kernel(
    const short* __restrict__ Q, const short* __restrict__ Kx,
    const short* __restrict__ V, short* __restrict__ O, int ld)
{
    constexpr int MF = S / 16;
    constexpr int SP = 32;
    __shared__ __align__(16) short P_lds[S * SP];
    __shared__ __align__(16) short Vt[64 * SP];

    const int lane = threadIdx.x;
    const int pair = blockIdx.x;
    const int head = pair & 7;
    const int bf = pair >> 3;
    long base; int stride;
    if (PASS == 0)      { base = (long)(bf >> 10) * 16384 + (bf & 1023); stride = 1024; }
    else if (PASS == 1) { int b = bf >> 9, t = (bf >> 5) & 15, w = bf & 31; base = (long)b * 16384 + t * 1024 + w; stride = 32; }
    else                { int b = bf >> 9, t = (bf >> 5) & 15, h = bf & 31; base = (long)b * 16384 + t * 1024 + (h << 5); stride = 1; }
    const int hoff = head * 64;

    if (S == 16) {   // zero-pad P (k>=16) and Vt (kv>=16)
        short8 z = {0, 0, 0, 0, 0, 0, 0, 0};
        *(short8*)(P_lds + lane * 8) = z;
#pragma unroll
        for (int i = 0; i < 4; i++) *(short8*)(Vt + lane * 32 + i * 8) = z;
        __syncthreads();
    }

    // Q/K fragments: A lane holds A[lane&15][(lane>>4)*8+e]; B lane holds B[(lane>>4)*8+e][lane&15]=K[lane&15][k]
    short8 qf[MF][2], kf[MF][2];
#pragma unroll
    for (int f = 0; f < MF; f++) {
        int r = f * 16 + (lane & 15);
        const short* qp = Q + (base + (long)r * stride) * ld + hoff + ((lane >> 4) * 8);
        qf[f][0] = *(const short8*)qp;
        qf[f][1] = *(const short8*)(qp + 32);
        const short* kp = Kx + (base + (long)r * stride) * ld + hoff + ((lane >> 4) * 8);
        kf[f][0] = *(const short8*)kp;
        kf[f][1] = *(const short8*)(kp + 32);
    }

    // stage V^T into LDS
    short8 vv[4];
    const int vr  = (S == 32) ? (lane & 31) : (lane & 15);
    const int vd0 = (S == 32) ? ((lane >> 5) * 32) : ((lane >> 4) * 16);
    constexpr int NVC = (S == 32) ? 4 : 2;
    {
        const short* vp = V + (base + (long)vr * stride) * ld + hoff + vd0;
#pragma unroll
        for (int c = 0; c < NVC; c++) vv[c] = *(const short8*)(vp + c * 8);
    }
#pragma unroll
    for (int c = 0; c < NVC; c++)
#pragma unroll
        for (int e = 0; e < 8; e++)
            Vt[(vd0 + c * 8 + e) * SP + vr] = vv[c][e];

    // scores S[q][k] = sum_d Q[q][d] K[k][d]
    f32x4 zero4 = {0.f, 0.f, 0.f, 0.f};
    f32x4 sc[MF][MF];
#pragma unroll
    for (int i = 0; i < MF; i++)
#pragma unroll
        for (int j = 0; j < MF; j++) {
            f32x4 a = __builtin_amdgcn_mfma_f32_16x16x32_bf16(qf[i][0], kf[j][0], zero4, 0, 0, 0);
            sc[i][j] = __builtin_amdgcn_mfma_f32_16x16x32_bf16(qf[i][1], kf[j][1], a, 0, 0, 0);
        }

    // softmax over k (cols); row = i*16 + (lane>>4)*4 + r, col = (lane&15) + 16*j
#pragma unroll
    for (int i = 0; i < MF; i++) {
#pragma unroll
        for (int r = 0; r < 4; r++) {
            float mx = sc[i][0][r];
            if (MF == 2) mx = fmaxf(mx, sc[i][1][r]);
#pragma unroll
            for (int m = 1; m < 16; m <<= 1) mx = fmaxf(mx, __shfl_xor(mx, m, 64));
            float e0 = expf(sc[i][0][r] - mx);
            float e1 = (MF == 2) ? expf(sc[i][1][r] - mx) : 0.f;
            float sum = e0 + e1;
#pragma unroll
            for (int m = 1; m < 16; m <<= 1) sum += __shfl_xor(sum, m, 64);
            float inv = 1.f / sum;
            int row = i * 16 + ((lane >> 4) << 2) + r;
            P_lds[row * SP + (lane & 15)] = f2bf(e0 * inv);
            if (MF == 2) P_lds[row * SP + 16 + (lane & 15)] = f2bf(e1 * inv);
        }
    }
    __syncthreads();

    // O = P (M=S,K=SP) * V (SP x 64)
    short8 pa[MF];
#pragma unroll
    for (int f = 0; f < MF; f++)
        pa[f] = *(const short8*)(P_lds + (f * 16 + (lane & 15)) * SP + (lane >> 4) * 8);
    short8 vbf[4];
#pragma unroll
    for (int n = 0; n < 4; n++)
        vbf[n] = *(const short8*)(Vt + (n * 16 + (lane & 15)) * SP + (lane >> 4) * 8);
    f32x4 of[MF][4];
#pragma unroll
    for (int f = 0; f < MF; f++)
#pragma unroll
        for (int n = 0; n < 4; n++)
            of[f][n] = __builtin_amdgcn_mfma_f32_16x16x32_bf16(pa[f], vbf[n], zero4, 0, 0, 0);

#pragma unroll
    for (int f = 0; f < MF; f++) {
        int q0 = f * 16 + ((lane >> 4) << 2);
#pragma unroll
        for (int n = 0; n < 4; n++) {
            int d = n * 16 + (lane & 15);
#pragma unroll
            for (int r = 0; r < 4; r++)
                O[(base + (long)(q0 + r) * stride) * 512 + hoff + d] = f2bf(of[f][n][r]);
        }
    }
}

// ---------------- launch ----------
extern "C" void kernel_launch(void* const* d_in, const int* in_sizes, int n_in,
                              void* d_out, int out_size, void* d_ws, size_t ws_size,
                              hipStream_t stream)
{
    const float* x   = (const float*)d_in[0];
    const float* lns = (const float*)d_in[1];
    const float* lnb = (const float*)d_in[2];
    const float* wq  = (const float*)d_in[3];
    const float* bq  = (const float*)d_in[4];
    const float* wk  = (const float*)d_in[5];
    const float* bk  = (const float*)d_in[6];
    const float* wv  = (const float*)d_in[7];
    const float* bv  = (const float*)d_in[8];
    const float* wo  = (const float*)d_in[9];
    const float* bo  = (const float*)d_in[10];
    const float* lms = (const float*)d_in[11];
    const float* lmb = (const float*)d_in[12];
    const float* w1  = (const float*)d_in[13];
    const float* b1  = (const float*)d_in[14];
    const float* w2  = (const float*)d_in[15];
    const float* b2  = (const float*)d_in[16];

    char* ws = (char*)d_ws;
    short* wT   = (short*)ws;                          // 10,485,760 B
    short* bufA = (short*)(ws + 10485760);             // 33,554,432 B  (LN out / attn out)
    short* big  = (short*)(ws + 10485760 + 33554432);  // 134,217,728 B (QKV [M][1536] then h1 [M][2048])
    float* xcur = (float*)d_out;                       // fp32 residual stream lives in d_out

    const int M = 32768;

    cvt_weights<<<20480, 256, 0, stream>>>(wq, wk, wv, wo, w1, w2, wT);

    for (int p = 0; p < 3; ++p) {
        const float* xin = (p == 0) ? x : xcur;
        ln_kernel<<<8192, 256, 0, stream>>>(xin, lns + p * 512, lnb + p * 512, bufA);
        const short* wqkvT = wT + (long)(p * 4) * 262144;      // q,k,v contiguous [1536][512]
        const short* woT   = wT + (long)(p * 4 + 3) * 262144;
        gemm_nt<3><<<dim3(256, 12), 256, 0, stream>>>(bufA, wqkvT,
            bq + p * 512, bk + p * 512, bv + p * 512,
            nullptr, nullptr, big, M, 1536, 512, 0.125f);
        const short* qb = big, *kb = big + 512, *vbp = big + 1024;
        if (p == 0)      attn_kernel<16, 0><<<16384, 64, 0, stream>>>(qb, kb, vbp, bufA, 1536);
        else if (p == 1) attn_kernel<32, 1><<<8192, 64, 0, stream>>>(qb, kb, vbp, bufA, 1536);
        else             attn_kernel<32, 2><<<8192, 64, 0, stream>>>(qb, kb, vbp, bufA, 1536);
        gemm_nt<1><<<dim3(256, 4), 256, 0, stream>>>(bufA, woT,
            bo + p * 512, nullptr, nullptr, xin, xcur, nullptr, M, 512, 512, 1.f);
    }

    ln_kernel<<<8192, 256, 0, stream>>>(xcur, lms, lmb, bufA);
    const short* w1T = wT + 12L * 262144;
    const short* w2T = wT + 12L * 262144 + 1048576;
    gemm_nt<2><<<dim3(256, 16), 256, 0, stream>>>(bufA, w1T, b1,
        nullptr, nullptr, nullptr, nullptr, big, M, 2048, 512, 1.f);
    gemm_nt<1><<<dim3(256, 4), 256, 0, stream>>>(big, w2T, b2,
        nullptr, nullptr, xcur, xcur, nullptr, M, 512, 2048, 1.f);
}